// Round 5
// baseline (2950.926 us; speedup 1.0000x reference)
//
#include <hip/hip_runtime.h>
#include <cmath>

// CustomRNNCell: h_{t+1} = tanh(h_t @ W_h^T + b_h + x_t @ W_x^T + b_x)
// B=64, T=512, H=I=1024. Output: h_final [64,1024] fp32.
//
// R5: single fused persistent scan. Pre-pass converts x -> bf16 [T][B][H].
// Scan blocks hold BOTH W_h and W_x 32-col slices in LDS (129 KB). Per step:
// x_t@Wx accumulated first (no dependency -- fills the h-flag wait shadow),
// then h_t@Wh chunks as producer flags arrive. Sync is WAVE-granular:
// each wave drains its own coherent stores (s_waitcnt 0) and publishes its
// own flag; no per-step __syncthreads. h exchanged in A-fragment-major
// layout via L2-bypassing relaxed agent atomics (R3/R4 scheme).

#define Bsz 64
#define Tsz 512
#define Hsz 1024

typedef float  f32x4 __attribute__((ext_vector_type(4)));
typedef short  s16x8 __attribute__((ext_vector_type(8)));

__device__ __forceinline__ unsigned short f2bf(float f) {
  unsigned u = __float_as_uint(f);
  u += 0x7fff + ((u >> 16) & 1);   // round-to-nearest-even (finite inputs)
  return (unsigned short)(u >> 16);
}

__device__ __forceinline__ void pack8(unsigned short* d, float4 v0, float4 v1) {
  d[0] = f2bf(v0.x); d[1] = f2bf(v0.y); d[2] = f2bf(v0.z); d[3] = f2bf(v0.w);
  d[4] = f2bf(v1.x); d[5] = f2bf(v1.y); d[6] = f2bf(v1.z); d[7] = f2bf(v1.w);
}

__device__ __forceinline__ float fast_tanh(float x) {
  float e = __expf(2.0f * x);
  return 1.0f - 2.0f / (e + 1.0f);
}

// ---------------- Pre-pass: x fp32 [B][T][H] -> bf16 [T][B][H] ----------------
__global__ __launch_bounds__(128) void x_convert_kernel(
    const float* __restrict__ x, unsigned short* __restrict__ xb) {
  const int row = blockIdx.x;          // b*512 + t
  const int b = row >> 9, t = row & 511;
  const float* src = x + (size_t)row * Hsz + threadIdx.x * 8;
  union { unsigned short s[8]; s16x8 v; } u;
  pack8(u.s, *(const float4*)src, *(const float4*)(src + 4));
  *(s16x8*)(xb + (size_t)t * (Bsz * Hsz) + b * Hsz + threadIdx.x * 8) = u.v;
}

// ---------------- Fused persistent scan ----------------
// 128 blocks x 128 threads (2 waves). Block (gb,gj): rows gb*16..+15,
// cols gj*32..+31; wave w -> 16 cols. h buffers: per group 16384 bf16 as
// 32 chunks of 512: chunk c elem (q*128 + m*8 + j), k = c*32+q*8+j.
// Wave w's half = [c*512 + w*256, +256). Flags: 64 per group (chunk*2+w).
__global__ __launch_bounds__(128) void rnn_scan_kernel(
    const float* __restrict__ Wh, const float* __restrict__ Wx,
    const float* __restrict__ bh, const float* __restrict__ bx,
    const unsigned short* __restrict__ xb,
    float* __restrict__ out,
    unsigned short* __restrict__ h0buf, unsigned short* __restrict__ h1buf,
    unsigned* __restrict__ flags) {
  __shared__ unsigned short Wl[32 * 1024];   // 64 KB  W_h slice
  __shared__ unsigned short Wxl[32 * 1024];  // 64 KB  W_x slice
  __shared__ unsigned short Tr[2][16 * 20];  // per-wave transpose scratch

  const int tid  = threadIdx.x;
  const int w    = tid >> 6;
  const int lane = tid & 63;
  const int m    = lane & 15;
  const int q    = lane >> 4;
  const int gb   = blockIdx.x >> 5;   // 0..3  batch group
  const int gj   = blockIdx.x & 31;   // 0..31 col group (== chunk id)
  const int rb   = gb * 16;
  const int j0   = gj * 32;

  // Stage W_h and W_x slices (rows j0..j0+31) to LDS, chunk-swizzled
  for (int jr = 0; jr < 32; ++jr) {
    const float* ph = Wh + (size_t)(j0 + jr) * 1024 + tid * 8;
    const float* px = Wx + (size_t)(j0 + jr) * 1024 + tid * 8;
    const int sw = ((((unsigned)tid) ^ (jr & 7)) << 3);
    pack8(&Wl[jr * 1024 + sw],  *(const float4*)ph, *(const float4*)(ph + 4));
    pack8(&Wxl[jr * 1024 + sw], *(const float4*)px, *(const float4*)(px + 4));
  }
  __syncthreads();

  const int colg = j0 + w * 16 + m;   // output col this lane produces
  const int jl   = w * 16 + m;        // local W row (B-operand col)
  const float bias = bx[colg] + bh[colg];

  unsigned* grpflags = flags + gb * 64 * 16;          // 64-B strided slots
  unsigned* myflag   = grpflags + (gj * 2 + w) * 16;  // this wave's flag
  const unsigned* pollflag = grpflags + lane * 16;    // lane L polls flag L

  // transpose read indices (constant per lane)
  const int t_br = (lane >> 1) & 15;
  const int t_c0 = (lane >> 5) * 8 + (lane & 1) * 4;

  for (int t = 0; t < Tsz; ++t) {
    const unsigned short* hc = (t & 1) ? h1buf : h0buf;
    unsigned short*       hn = (t & 1) ? h0buf : h1buf;

    f32x4 acc0 = (f32x4){0.f, 0.f, 0.f, 0.f};
    f32x4 acc1 = (f32x4){0.f, 0.f, 0.f, 0.f};

    // ---- x-part: x_t @ Wx^T (no cross-block dependency) ----
    const unsigned short* xrow = xb + (size_t)t * (Bsz * Hsz) + (rb + m) * Hsz;
#pragma unroll
    for (int g = 0; g < 4; ++g) {
      s16x8 xa[8];
#pragma unroll
      for (int j = 0; j < 8; ++j)
        xa[j] = *(const s16x8*)(xrow + (g * 8 + j) * 32 + q * 8);
#pragma unroll
      for (int j = 0; j < 8; ++j) {
        const int c4 = (g * 8 + j) * 4 + q;
        s16x8 b = *(const s16x8*)&Wxl[jl * 1024 + ((c4 ^ (jl & 7)) << 3)];
        if (j & 1)
          acc1 = __builtin_amdgcn_mfma_f32_16x16x32_bf16(xa[j], b, acc1, 0, 0, 0);
        else
          acc0 = __builtin_amdgcn_mfma_f32_16x16x32_bf16(xa[j], b, acc0, 0, 0, 0);
      }
    }

    // ---- h-part: h_t @ Wh^T, chunks as producer flags arrive ----
    if (t > 0) {
      const unsigned long long* src =
          (const unsigned long long*)(hc + gb * 16384);
      const int loff = (q * 16 + m) * 2;   // u64 offset within a chunk

      // watermark over chunk PAIRS of per-wave flags
      unsigned v = __hip_atomic_load(pollflag, __ATOMIC_RELAXED,
                                     __HIP_MEMORY_SCOPE_AGENT);
      unsigned long long rdy = __ballot(v >= (unsigned)t);
      unsigned long long nr = ~(rdy & (rdy >> 1)) & 0x5555555555555555ull;
      int wm = nr ? (int)(__builtin_ctzll(nr) >> 1) : 32;
#pragma unroll
      for (int g = 0; g < 4; ++g) {
        while (wm < (g + 1) * 8) {
          __builtin_amdgcn_s_sleep(1);
          unsigned v2 = __hip_atomic_load(pollflag, __ATOMIC_RELAXED,
                                          __HIP_MEMORY_SCOPE_AGENT);
          unsigned long long r2 = __ballot(v2 >= (unsigned)t);
          unsigned long long n2 = ~(r2 & (r2 >> 1)) & 0x5555555555555555ull;
          wm = n2 ? (int)(__builtin_ctzll(n2) >> 1) : 32;
        }
        union { unsigned long long u[2]; s16x8 v; } a[8];
#pragma unroll
        for (int j = 0; j < 8; ++j) {
          const unsigned long long* cp = src + (g * 8 + j) * 128 + loff;
          a[j].u[0] = __hip_atomic_load(cp,     __ATOMIC_RELAXED, __HIP_MEMORY_SCOPE_AGENT);
          a[j].u[1] = __hip_atomic_load(cp + 1, __ATOMIC_RELAXED, __HIP_MEMORY_SCOPE_AGENT);
        }
#pragma unroll
        for (int j = 0; j < 8; ++j) {
          const int c4 = (g * 8 + j) * 4 + q;
          s16x8 b = *(const s16x8*)&Wl[jl * 1024 + ((c4 ^ (jl & 7)) << 3)];
          if (j & 1)
            acc1 = __builtin_amdgcn_mfma_f32_16x16x32_bf16(a[j].v, b, acc1, 0, 0, 0);
          else
            acc0 = __builtin_amdgcn_mfma_f32_16x16x32_bf16(a[j].v, b, acc0, 0, 0, 0);
        }
      }
    }
    f32x4 acc = acc0 + acc1;

    float hv[4];
#pragma unroll
    for (int r = 0; r < 4; ++r) hv[r] = fast_tanh(acc[r] + bias);

    if (t == Tsz - 1) {
#pragma unroll
      for (int r = 0; r < 4; ++r)
        out[(rb + q * 4 + r) * Hsz + colg] = hv[r];
    } else {
      // per-wave 16x16 transpose: C-layout -> A-frag-major (R4-proven fences)
      unsigned short* S = &Tr[w][0];
#pragma unroll
      for (int r = 0; r < 4; ++r)
        S[(q * 4 + r) * 20 + m] = f2bf(hv[r]);
      __asm__ __volatile__("" ::: "memory");
      unsigned long long tv =
          *(const volatile unsigned long long*)&S[t_br * 20 + t_c0];
      __asm__ __volatile__("" ::: "memory");
      unsigned long long* dst =
          (unsigned long long*)(hn + gb * 16384 + gj * 512 + w * 256) + lane;
      __hip_atomic_store(dst, tv, __ATOMIC_RELAXED, __HIP_MEMORY_SCOPE_AGENT);

      // wave-granular: drain own stores, then publish own flag
      __builtin_amdgcn_s_waitcnt(0);
      __asm__ __volatile__("" ::: "memory");
      if (lane == 0)
        __hip_atomic_store(myflag, (unsigned)(t + 1), __ATOMIC_RELAXED,
                           __HIP_MEMORY_SCOPE_AGENT);
      __asm__ __volatile__("" ::: "memory");
    }
  }
}

extern "C" void kernel_launch(void* const* d_in, const int* in_sizes, int n_in,
                              void* d_out, int out_size, void* d_ws, size_t ws_size,
                              hipStream_t stream) {
  (void)in_sizes; (void)n_in; (void)out_size; (void)ws_size;
  const float* x  = (const float*)d_in[0];  // [64,512,1024]
  const float* Wh = (const float*)d_in[1];  // [1024,1024]
  const float* bh = (const float*)d_in[2];  // [1024]
  const float* Wx = (const float*)d_in[3];  // [1024,1024]
  const float* bx = (const float*)d_in[4];  // [1024]
  float* out = (float*)d_out;               // [64,1024]

  char* ws = (char*)d_ws;
  unsigned*       flags = (unsigned*)ws;                      // 16 KB
  unsigned short* h0    = (unsigned short*)(ws + 65536);      // 128 KB
  unsigned short* h1    = (unsigned short*)(ws + 65536 + 131072);
  unsigned short* xb    = (unsigned short*)(ws + (1 << 20));  // 64 MB bf16 x

  // zero flags (ws re-poisoned each call; h buffers need no init: t=0 skips h)
  hipMemsetAsync(d_ws, 0, 16384, stream);

  x_convert_kernel<<<dim3(Bsz * Tsz), dim3(128), 0, stream>>>(x, xb);
  rnn_scan_kernel<<<dim3(128), dim3(128), 0, stream>>>(
      Wh, Wx, bh, bx, xb, out, h0, h1, flags);
}

// Round 6
// 2120.112 us; speedup vs baseline: 1.3919x; 1.3919x over previous
//
#include <hip/hip_runtime.h>
#include <cmath>

// CustomRNNCell: h_{t+1} = tanh(h_t @ W_h^T + b_h + x_t @ W_x^T + b_x)
// B=64, T=512, H=I=1024. Output: h_final [64,1024] fp32.
//
// R6: ONE kernel, block-specialized:
//   blocks 0..127   : R4 scan (unchanged mechanics), gated per step on xp
//                     chunk readiness (t-chunks of 8).
//   blocks 128..383 : xp GEMM producers, t-ascending tiles (1 t x 32 b x 64 j),
//                     coherent (MALL write-through) xp stores, arrival counter
//                     per t-chunk. Producers never wait -> no deadlock.
// xp layout [t][b][j] fp32 (r = t*64+b). Bias added in scan epilogue.

#define Bsz 64
#define Tsz 512
#define Hsz 1024

typedef float  f32x4 __attribute__((ext_vector_type(4)));
typedef short  s16x8 __attribute__((ext_vector_type(8)));

__device__ __forceinline__ unsigned short f2bf(float f) {
  unsigned u = __float_as_uint(f);
  u += 0x7fff + ((u >> 16) & 1);   // round-to-nearest-even (finite inputs)
  return (unsigned short)(u >> 16);
}

__device__ __forceinline__ void pack8(unsigned short* d, float4 v0, float4 v1) {
  d[0] = f2bf(v0.x); d[1] = f2bf(v0.y); d[2] = f2bf(v0.z); d[3] = f2bf(v0.w);
  d[4] = f2bf(v1.x); d[5] = f2bf(v1.y); d[6] = f2bf(v1.z); d[7] = f2bf(v1.w);
}

__device__ __forceinline__ float fast_tanh(float x) {
  float e = __expf(2.0f * x);
  return 1.0f - 2.0f / (e + 1.0f);
}

// flags layout (u32 idx): [0..2047] h-flags (gb*512 + slot*16)
//                         [2048..3071] xp chunk arrival counters (i*16)
__global__ __launch_bounds__(128) void rnn_fused_kernel(
    const float* __restrict__ Wh, const float* __restrict__ Wx,
    const float* __restrict__ bh, const float* __restrict__ bx,
    const float* __restrict__ x, float* __restrict__ xp,
    float* __restrict__ out,
    unsigned short* __restrict__ h0buf, unsigned short* __restrict__ h1buf,
    unsigned* __restrict__ flags) {
  __shared__ unsigned short Wl[32 * 1024];   // scan: W_h slice | prod: A/B tiles
  __shared__ unsigned short Tr[2][16 * 20];  // scan: transpose scratch

  const int tid  = threadIdx.x;
  const int w    = tid >> 6;
  const int lane = tid & 63;
  const int m    = lane & 15;
  const int q    = lane >> 4;

  if (blockIdx.x < 128) {
    // ==================== SCAN ROLE (R4-proven) ====================
    const int gb = blockIdx.x >> 5;   // 0..3  batch group
    const int gj = blockIdx.x & 31;   // 0..31 col group (== chunk id)
    const int rb = gb * 16;
    const int j0 = gj * 32;

    for (int jr = 0; jr < 32; ++jr) {
      const float* p = Wh + (size_t)(j0 + jr) * 1024 + tid * 8;
      unsigned short* d = &Wl[jr * 1024 + ((((unsigned)tid) ^ (jr & 7)) << 3)];
      pack8(d, *(const float4*)p, *(const float4*)(p + 4));
    }
    __syncthreads();

    const int colg = j0 + w * 16 + m;
    const int jl   = w * 16 + m;
    const float bias = bx[colg] + bh[colg];

    unsigned* grpflags = flags + gb * 512;
    unsigned* myflag   = grpflags + gj * 16;
    const unsigned* pollflag = grpflags + (lane & 31) * 16;

    const int t_br = (lane >> 1) & 15;
    const int t_c0 = (lane >> 5) * 8 + (lane & 1) * 4;

    for (int t = 0; t < Tsz; ++t) {
      const unsigned short* hc = (t & 1) ? h1buf : h0buf;
      unsigned short*       hn = (t & 1) ? h0buf : h1buf;

      // gate on xp t-chunk readiness (producers run ~40 chunks ahead)
      const unsigned* xcnt = flags + 2048 + ((t >> 3) << 4);
      while (__hip_atomic_load(xcnt, __ATOMIC_RELAXED,
                               __HIP_MEMORY_SCOPE_AGENT) < 256u)
        __builtin_amdgcn_s_sleep(2);
      __asm__ __volatile__("" ::: "memory");

      // xp_t loads (hide behind h-poll below)
      float xv[4];
#pragma unroll
      for (int r = 0; r < 4; ++r)
        xv[r] = xp[(size_t)(t * 64 + rb + q * 4 + r) * Hsz + colg];

      f32x4 acc0 = (f32x4){0.f, 0.f, 0.f, 0.f};
      f32x4 acc1 = (f32x4){0.f, 0.f, 0.f, 0.f};

      if (t > 0) {
        const unsigned long long* src =
            (const unsigned long long*)(hc + gb * 16384);
        const int loff = (q * 16 + m) * 2;

        unsigned v = __hip_atomic_load(pollflag, __ATOMIC_RELAXED,
                                       __HIP_MEMORY_SCOPE_AGENT);
        int wm = (int)__builtin_ctzll(~__ballot(v >= (unsigned)t) |
                                      0xFFFFFFFF00000000ull);
#pragma unroll
        for (int g = 0; g < 4; ++g) {
          while (wm < (g + 1) * 8) {
            __builtin_amdgcn_s_sleep(1);
            unsigned v2 = __hip_atomic_load(pollflag, __ATOMIC_RELAXED,
                                            __HIP_MEMORY_SCOPE_AGENT);
            wm = (int)__builtin_ctzll(~__ballot(v2 >= (unsigned)t) |
                                      0xFFFFFFFF00000000ull);
          }
          union { unsigned long long u[2]; s16x8 v; } a[8];
#pragma unroll
          for (int j = 0; j < 8; ++j) {
            const unsigned long long* cp = src + (g * 8 + j) * 128 + loff;
            a[j].u[0] = __hip_atomic_load(cp,     __ATOMIC_RELAXED, __HIP_MEMORY_SCOPE_AGENT);
            a[j].u[1] = __hip_atomic_load(cp + 1, __ATOMIC_RELAXED, __HIP_MEMORY_SCOPE_AGENT);
          }
#pragma unroll
          for (int j = 0; j < 8; ++j) {
            const int c4 = (g * 8 + j) * 4 + q;
            s16x8 b = *(const s16x8*)&Wl[jl * 1024 + ((c4 ^ (jl & 7)) << 3)];
            if (j & 1)
              acc1 = __builtin_amdgcn_mfma_f32_16x16x32_bf16(a[j].v, b, acc1, 0, 0, 0);
            else
              acc0 = __builtin_amdgcn_mfma_f32_16x16x32_bf16(a[j].v, b, acc0, 0, 0, 0);
          }
        }
      }
      f32x4 acc = acc0 + acc1;

      float hv[4];
#pragma unroll
      for (int r = 0; r < 4; ++r) hv[r] = fast_tanh(acc[r] + xv[r] + bias);

      if (t == Tsz - 1) {
#pragma unroll
        for (int r = 0; r < 4; ++r)
          out[(rb + q * 4 + r) * Hsz + colg] = hv[r];
      } else {
        unsigned short* S = &Tr[w][0];
#pragma unroll
        for (int r = 0; r < 4; ++r)
          S[(q * 4 + r) * 20 + m] = f2bf(hv[r]);
        __asm__ __volatile__("" ::: "memory");
        unsigned long long tv =
            *(const volatile unsigned long long*)&S[t_br * 20 + t_c0];
        __asm__ __volatile__("" ::: "memory");
        unsigned long long* dst =
            (unsigned long long*)(hn + gb * 16384 + gj * 512 + w * 256) + lane;
        __hip_atomic_store(dst, tv, __ATOMIC_RELAXED, __HIP_MEMORY_SCOPE_AGENT);

        __syncthreads();   // drains vmcnt for both waves
        if (tid == 0)
          __hip_atomic_store(myflag, (unsigned)(t + 1), __ATOMIC_RELAXED,
                             __HIP_MEMORY_SCOPE_AGENT);
      }
    }
  } else {
    // ==================== PRODUCER ROLE: xp GEMM ====================
    // 256 blocks, 64 iterations; iter i covers t in [8i, 8i+8).
    // Tile = 1 timestep x 32 batch x 64 cols, K=1024 staged 32/iter in LDS.
    unsigned short* Al = Wl;          // 32 x 32 bf16
    unsigned short* Bl = Wl + 1024;   // 64 x 32 bf16

    const int p = blockIdx.x - 128;
    const int srA = tid >> 2, scA = tid & 3;
    const int swA = scA ^ ((srA >> 1) & 3);
    const int srB = tid >> 1, cB0 = (tid & 1) * 2, cB1 = cB0 + 1;
    const int swB0 = cB0 ^ ((srB >> 1) & 3), swB1 = cB1 ^ ((srB >> 1) & 3);
    const int arow = w * 16 + m;
    const int aoff = arow * 32 + ((q ^ ((arow >> 1) & 3)) << 3);

    for (int i = 0; i < 64; ++i) {
      const int tile = i * 256 + p;
      const int mt = tile >> 4, ny = tile & 15;
      const int r0 = mt * 32, n0 = ny * 64;
      const int tt = r0 >> 6;          // timestep of this tile
      const int b0 = r0 & 63;          // 0 or 32

      f32x4 acc[4];
#pragma unroll
      for (int k = 0; k < 4; ++k) acc[k] = (f32x4){0.f, 0.f, 0.f, 0.f};

      for (int kt = 0; kt < 32; ++kt) {
        const float* pa = x + ((size_t)(b0 + srA) * 512 + tt) * 1024 + kt * 32 + scA * 8;
        pack8(&Al[srA * 32 + swA * 8], *(const float4*)pa, *(const float4*)(pa + 4));
        const float* pb = Wx + (size_t)(n0 + srB) * 1024 + kt * 32 + cB0 * 8;
        pack8(&Bl[srB * 32 + swB0 * 8], *(const float4*)pb, *(const float4*)(pb + 4));
        pack8(&Bl[srB * 32 + swB1 * 8], *(const float4*)(pb + 8), *(const float4*)(pb + 12));
        __syncthreads();
        s16x8 a = *(const s16x8*)&Al[aoff];
#pragma unroll
        for (int nt = 0; nt < 4; ++nt) {
          const int nrow = nt * 16 + m;
          s16x8 b = *(const s16x8*)&Bl[nrow * 32 + ((q ^ ((nrow >> 1) & 3)) << 3)];
          acc[nt] = __builtin_amdgcn_mfma_f32_16x16x32_bf16(a, b, acc[nt], 0, 0, 0);
        }
        __syncthreads();
      }

      // epilogue: coherent (write-through) stores -> visible at MALL
#pragma unroll
      for (int nt = 0; nt < 4; ++nt) {
        const int col = n0 + nt * 16 + m;
#pragma unroll
        for (int rr = 0; rr < 4; ++rr) {
          const int r = r0 + w * 16 + q * 4 + rr;
          __hip_atomic_store(xp + (size_t)r * 1024 + col, acc[nt][rr],
                             __ATOMIC_RELAXED, __HIP_MEMORY_SCOPE_AGENT);
        }
      }
      __builtin_amdgcn_s_waitcnt(0);     // this wave's stores at MALL
      __asm__ __volatile__("" ::: "memory");
      __syncthreads();                    // both waves drained
      if (tid == 0)
        __hip_atomic_fetch_add(flags + 2048 + (i << 4), 1u,
                               __ATOMIC_RELAXED, __HIP_MEMORY_SCOPE_AGENT);
    }
  }
}

extern "C" void kernel_launch(void* const* d_in, const int* in_sizes, int n_in,
                              void* d_out, int out_size, void* d_ws, size_t ws_size,
                              hipStream_t stream) {
  (void)in_sizes; (void)n_in; (void)out_size; (void)ws_size;
  const float* x  = (const float*)d_in[0];  // [64,512,1024]
  const float* Wh = (const float*)d_in[1];  // [1024,1024]
  const float* bh = (const float*)d_in[2];  // [1024]
  const float* Wx = (const float*)d_in[3];  // [1024,1024]
  const float* bx = (const float*)d_in[4];  // [1024]
  float* out = (float*)d_out;               // [64,1024]

  char* ws = (char*)d_ws;
  unsigned*       flags = (unsigned*)ws;                      // 12 KB used
  unsigned short* h0    = (unsigned short*)(ws + 65536);      // 128 KB
  unsigned short* h1    = (unsigned short*)(ws + 65536 + 131072);
  float*          xp    = (float*)(ws + (1 << 20));           // 128 MB fp32

  // zero h-flags + xp arrival counters (ws re-poisoned each call)
  hipMemsetAsync(d_ws, 0, 16384, stream);

  rnn_fused_kernel<<<dim3(384), dim3(128), 0, stream>>>(
      Wh, Wx, bh, bx, x, xp, out, h0, h1, flags);
}